// Round 10
// baseline (1285.554 us; speedup 1.0000x reference)
//
#include <hip/hip_runtime.h>

#define HID 256
#define OBS 1024
#define SEQ 50
#define BATCH 32
#define SO (SEQ*OBS)   // 51200
#define NBLK 256
#define NTHR 256
#define NGRP 16
#define GSZ  16

#define F_TRANSA   1
#define F_NEGID    2
#define F_ACC      4
#define F_TRANSB   8
#define F_SCALECOL 16

struct DevWS {
  float ub[2][HID][HID];     // 0,1  normalized reflectors (bitrev order)
  float Mm[2][HID][HID];     // 2,3  M = 2(I+2L)^-1, lower triangular
  float C2[2][HID][HID];     // 4,5  reflector Gram
  float ZT[2][HID][HID];     // 6,7  ZT = M @ ub
  float U[HID][HID];         // 8
  float V[HID][HID];         // 9
  float A[HID][HID];         // 10
  float A2[HID][HID];        // 11
  float A4[HID][HID];        // 12
  float A8[HID][HID];        // 13
  float A16[HID][HID];       // 14
  float A32[HID][HID];       // 15
  float Cg[HID][HID];        // 16  C^T C
  float G2[HID][HID];        // 17
  float Grun[HID][HID];      // 18
  float T[HID][HID];         // 19
  float T2[HID][HID];        // 20
  float G18[HID][HID];       // 21
  float G32b[HID][HID];      // 22
  float Gfin[HID][HID];      // 23
  float Zt4[SEQ][4][HID*BATCH];   // partial C^T Y_t per obs-quarter
  float Zt[SEQ][HID*BATCH];       // 24 reduced
  float Rb[2][25][HID*BATCH];     // 25,26 R-tree ping-pong
  float Cg4[4][HID][HID];         // K-split partials of C^T C
  float psum[NBLK+1];             // y^2 per block, logdet^2 at [NBLK]
  float s1b[BATCH];               // per-rhs sum alpha_j*rz_j
};
__device__ DevWS g;

// ---- hierarchical sense-reversing grid barrier ----
struct BarLine { unsigned v; unsigned pad[31]; };
__device__ BarLine g_grp[NGRP];               // zero-init, each on own 128B line
__device__ __align__(128) unsigned g_root = 0;
__device__ __align__(128) unsigned g_gen  = 0;

__device__ __forceinline__ void gridbar(){
  __threadfence();                 // release prior writes
  __syncthreads();
  if(threadIdx.x == 0){
    const int gid = blockIdx.x >> 4;       // 16 groups of 16
    unsigned gen = __hip_atomic_load(&g_gen, __ATOMIC_RELAXED, __HIP_MEMORY_SCOPE_AGENT);
    unsigned v = __hip_atomic_fetch_add(&g_grp[gid].v, 1u, __ATOMIC_ACQ_REL, __HIP_MEMORY_SCOPE_AGENT);
    if(v == (unsigned)(GSZ-1)){
      __hip_atomic_store(&g_grp[gid].v, 0u, __ATOMIC_RELAXED, __HIP_MEMORY_SCOPE_AGENT);
      unsigned u = __hip_atomic_fetch_add(&g_root, 1u, __ATOMIC_ACQ_REL, __HIP_MEMORY_SCOPE_AGENT);
      if(u == (unsigned)(NGRP-1)){
        __hip_atomic_store(&g_root, 0u, __ATOMIC_RELAXED, __HIP_MEMORY_SCOPE_AGENT);
        __hip_atomic_store(&g_gen, gen + 1u, __ATOMIC_RELEASE, __HIP_MEMORY_SCOPE_AGENT);
      }
    }
    while(__hip_atomic_load(&g_gen, __ATOMIC_RELAXED, __HIP_MEMORY_SCOPE_AGENT) == gen){
      __builtin_amdgcn_s_sleep(2);
    }
  }
  __syncthreads();
  __threadfence();                 // acquire
}

__device__ __forceinline__ float* sel(int c){
  switch(c){
    case 0:  return &g.ub[0][0][0];
    case 1:  return &g.ub[1][0][0];
    case 2:  return &g.Mm[0][0][0];
    case 3:  return &g.Mm[1][0][0];
    case 4:  return &g.C2[0][0][0];
    case 5:  return &g.C2[1][0][0];
    case 6:  return &g.ZT[0][0][0];
    case 7:  return &g.ZT[1][0][0];
    case 8:  return &g.U[0][0];
    case 9:  return &g.V[0][0];
    case 10: return &g.A[0][0];
    case 11: return &g.A2[0][0];
    case 12: return &g.A4[0][0];
    case 13: return &g.A8[0][0];
    case 14: return &g.A16[0][0];
    case 15: return &g.A32[0][0];
    case 16: return &g.Cg[0][0];
    case 17: return &g.G2[0][0];
    case 18: return &g.Grun[0][0];
    case 19: return &g.T[0][0];
    case 20: return &g.T2[0][0];
    case 21: return &g.G18[0][0];
    case 22: return &g.G32b[0][0];
    case 23: return &g.Gfin[0][0];
    case 24: return &g.Zt[0][0];
    case 25: return &g.Rb[0][0][0];
    default: return &g.Rb[1][0][0];
  }
}

__device__ __forceinline__ int bitrev8(int x){
  x = ((x & 0x55) << 1) | ((x >> 1) & 0x55);
  x = ((x & 0x33) << 2) | ((x >> 2) & 0x33);
  x = ((x & 0x0F) << 4) | ((x >> 4) & 0x0F);
  return x;
}

__device__ __forceinline__ float blkred(float v, float* sm){
  v += __shfl_down(v,32); v += __shfl_down(v,16); v += __shfl_down(v,8);
  v += __shfl_down(v,4);  v += __shfl_down(v,2);  v += __shfl_down(v,1);
  const int t = threadIdx.x;
  if((t&63)==0) sm[t>>6] = v;
  __syncthreads();
  float r = sm[0]+sm[1]+sm[2]+sm[3];
  __syncthreads();
  return r;
}

// ---------- 32x32-tile GEMM unit, register-hoisted loads ----------
__device__ void sq_tile(float* sm, int cA,int cB,int cC,int cD,int flags,int local,
                        const float* __restrict__ alpha){
  const float* A = sel(cA);
  const float* B = sel(cB);
  float* Cp = sel(cC);
  const float* Dp = sel(cD);
  float* As = sm; float* Bs = sm + 576;
  const int t = threadIdx.x, tx = t&15, ty = t>>4;
  const int m0 = (local>>3)*32, n0 = (local&7)*32;

  float2 aR[16], bR[16];
  #pragma unroll
  for(int c=0;c<16;c++){
    const int k0 = c*16;
    if(flags & F_TRANSA){
      int kk=t>>4, mm=(t&15)*2;
      aR[c] = *reinterpret_cast<const float2*>(&A[(k0+kk)*HID+m0+mm]);
    } else {
      int r=t>>3, cc=(t&7)*2;
      aR[c] = *reinterpret_cast<const float2*>(&A[(m0+r)*HID+k0+cc]);
    }
    if(flags & F_TRANSB){
      int cb=t>>3, rb=(t&7)*2;
      bR[c] = *reinterpret_cast<const float2*>(&B[(n0+cb)*HID+k0+rb]);
    } else {
      int rb=t>>4, cb=(t&15)*2;
      bR[c] = *reinterpret_cast<const float2*>(&B[(k0+rb)*HID+n0+cb]);
    }
  }
  float a00=0.f,a01=0.f,a10=0.f,a11=0.f;
  #pragma unroll 1
  for(int c=0;c<16;c++){
    if(flags & F_TRANSA){
      int kk=t>>4, mm=(t&15)*2;
      As[kk*36+mm]=aR[c].x; As[kk*36+mm+1]=aR[c].y;
    } else {
      int r=t>>3, cc=(t&7)*2;
      As[cc*36+r]=aR[c].x; As[(cc+1)*36+r]=aR[c].y;
    }
    if(flags & F_TRANSB){
      int cb=t>>3, rb=(t&7)*2;
      Bs[rb*36+cb]=bR[c].x; Bs[(rb+1)*36+cb]=bR[c].y;
    } else {
      int rb=t>>4, cb=(t&15)*2;
      Bs[rb*36+cb]=bR[c].x; Bs[rb*36+cb+1]=bR[c].y;
    }
    __syncthreads();
    #pragma unroll
    for(int kk=0;kk<16;kk++){
      float x0=As[kk*36+ty*2], x1=As[kk*36+ty*2+1];
      float y0=Bs[kk*36+tx*2], y1=Bs[kk*36+tx*2+1];
      a00+=x0*y0; a01+=x0*y1; a10+=x1*y0; a11+=x1*y1;
    }
    __syncthreads();
  }
  const int r=m0+ty*2, c=n0+tx*2;
  float v00=a00,v01=a01,v10=a10,v11=a11;
  if(flags & F_ACC){
    v00+=Dp[r*HID+c]; v01+=Dp[r*HID+c+1];
    v10+=Dp[(r+1)*HID+c]; v11+=Dp[(r+1)*HID+c+1];
  }
  if(flags & F_SCALECOL){
    float s0=1.f-fminf(fabsf(alpha[c]),1.f);
    float s1=1.f-fminf(fabsf(alpha[c+1]),1.f);
    v00*=s0; v01*=s1; v10*=s0; v11*=s1;
  }
  if(flags & F_NEGID){
    v00=((r==c)?1.f:0.f)-v00;   v01=((r==c+1)?1.f:0.f)-v01;
    v10=((r+1==c)?1.f:0.f)-v10; v11=((r+1==c+1)?1.f:0.f)-v11;
  }
  Cp[r*HID+c]=v00; Cp[r*HID+c+1]=v01;
  Cp[(r+1)*HID+c]=v10; Cp[(r+1)*HID+c+1]=v11;
}

// ---------- Cg partial: tile x K-split of C^T C ----------
__device__ void cgram_part(float* sm, int u, const float* __restrict__ Cm){
  const int tile = u>>2, ks = u&3;
  float* As = sm; float* Bs = sm + 576;
  const int t = threadIdx.x, tx = t&15, ty = t>>4;
  const int m0=(tile>>3)*32, n0=(tile&7)*32;
  const int r=t>>4, cp=(t&15)*2;
  float2 aR[16], bR[16];
  #pragma unroll
  for(int c=0;c<16;c++){
    const int o0 = ks*256 + c*16;
    aR[c] = *reinterpret_cast<const float2*>(&Cm[(o0+r)*HID+m0+cp]);
    bR[c] = *reinterpret_cast<const float2*>(&Cm[(o0+r)*HID+n0+cp]);
  }
  float a00=0.f,a01=0.f,a10=0.f,a11=0.f;
  #pragma unroll 1
  for(int c=0;c<16;c++){
    As[r*36+cp]=aR[c].x; As[r*36+cp+1]=aR[c].y;
    Bs[r*36+cp]=bR[c].x; Bs[r*36+cp+1]=bR[c].y;
    __syncthreads();
    #pragma unroll
    for(int kk=0;kk<16;kk++){
      float x0=As[kk*36+ty*2], x1=As[kk*36+ty*2+1];
      float y0=Bs[kk*36+tx*2], y1=Bs[kk*36+tx*2+1];
      a00+=x0*y0; a01+=x0*y1; a10+=x1*y0; a11+=x1*y1;
    }
    __syncthreads();
  }
  g.Cg4[ks][m0+ty*2][n0+tx*2]=a00;   g.Cg4[ks][m0+ty*2][n0+tx*2+1]=a01;
  g.Cg4[ks][m0+ty*2+1][n0+tx*2]=a10; g.Cg4[ks][m0+ty*2+1][n0+tx*2+1]=a11;
}

// ---------- Cg = sum of 4 partials (one 32x32 tile) ----------
__device__ void cgred_unit(int u){
  const int t=threadIdx.x;
  const int m0=(u>>3)*32, n0=(u&7)*32;
  const int e=t*4;
  const int mm=m0+(e>>5), nn=n0+(e&31);
  float4 a=*reinterpret_cast<const float4*>(&g.Cg4[0][mm][nn]);
  float4 b=*reinterpret_cast<const float4*>(&g.Cg4[1][mm][nn]);
  float4 c=*reinterpret_cast<const float4*>(&g.Cg4[2][mm][nn]);
  float4 d=*reinterpret_cast<const float4*>(&g.Cg4[3][mm][nn]);
  float4 r2; r2.x=(a.x+b.x)+(c.x+d.x); r2.y=(a.y+b.y)+(c.y+d.y);
  r2.z=(a.z+b.z)+(c.z+d.z); r2.w=(a.w+b.w)+(c.w+d.w);
  *reinterpret_cast<float4*>(&g.Cg[mm][nn]) = r2;
}

// ---------- normalize one reflector row ----------
__device__ void norm_unit(float* sm, int u, const float* __restrict__ Up,
                          const float* __restrict__ Vp){
  int mat=u>>8, j=u&255, src=bitrev8(j);
  const float* P = mat ? Vp : Up;
  int t=threadIdx.x;
  float x = P[src*HID + t];
  float ss = blkred(x*x, sm);
  g.ub[mat][j][t] = x * rsqrtf(ss);
}

// ---------- CtY partial with depth-8 C prefetch ----------
__device__ void cty_unit(float* sm, int u, const float* __restrict__ y,
                         const float* __restrict__ Cm){
  const int tt=u>>2, ot=u&3;
  float* ys = sm;   // [o][b] padded 36
  const int t=threadIdx.x;
  #pragma unroll
  for(int i=0;i<32;i++)
    ys[t*36 + i] = y[i*SO + tt*OBS + ot*256 + t];
  __syncthreads();
  const int h=t;
  float acc[32];
  #pragma unroll
  for(int z=0;z<32;z++) acc[z]=0.f;
  const float* Cp = &Cm[(ot*256)*HID + h];
  float cv[8], cvn[8];
  #pragma unroll
  for(int z=0;z<8;z++) cv[z] = Cp[z*HID];
  for(int o8=0;o8<256;o8+=8){
    if(o8+8<256){
      #pragma unroll
      for(int z=0;z<8;z++) cvn[z] = Cp[(o8+8+z)*HID];
    }
    #pragma unroll
    for(int z=0;z<8;z++){
      const float c = cv[z];
      const float* yr = &ys[(o8+z)*36];
      #pragma unroll
      for(int bb=0;bb<32;bb+=4){
        float4 v=*reinterpret_cast<const float4*>(&yr[bb]);
        acc[bb]+=c*v.x; acc[bb+1]+=c*v.y; acc[bb+2]+=c*v.z; acc[bb+3]+=c*v.w;
      }
    }
    #pragma unroll
    for(int z=0;z<8;z++) cv[z]=cvn[z];
  }
  float* outp = &g.Zt4[tt][ot][h*BATCH];
  #pragma unroll
  for(int bb=0;bb<32;bb+=4){
    float4 w={acc[bb],acc[bb+1],acc[bb+2],acc[bb+3]};
    *reinterpret_cast<float4*>(&outp[bb])=w;
  }
  __syncthreads();
}

// ---------- Zt[tt] = sum of 4 obs-quarter partials ----------
__device__ void ztred_unit(int u){
  const int t=threadIdx.x;
  const float* z=&g.Zt4[u][0][0];
  float* o=&g.Zt[u][0];
  for(int e=t*4; e<HID*BATCH; e+=NTHR*4){
    float4 a=*reinterpret_cast<const float4*>(&z[e]);
    float4 b=*reinterpret_cast<const float4*>(&z[HID*BATCH+e]);
    float4 c=*reinterpret_cast<const float4*>(&z[2*HID*BATCH+e]);
    float4 d=*reinterpret_cast<const float4*>(&z[3*HID*BATCH+e]);
    float4 r; r.x=(a.x+b.x)+(c.x+d.x); r.y=(a.y+b.y)+(c.y+d.y);
    r.z=(a.z+b.z)+(c.z+d.z); r.w=(a.w+b.w)+(c.w+d.w);
    *reinterpret_cast<float4*>(&o[e])=r;
  }
}

// ---------- M diag: 32x32 forward substitution + zero row slice ----------
__device__ void mdiag_unit(float* sm, int u){
  int mat=u>>3, p=u&7;
  float* Ls = sm; // [32][33]
  const int t=threadIdx.x;
  for(int e=t;e<1024;e+=256){
    int k=e>>5, i=e&31;
    Ls[k*33+i] = g.C2[mat][p*32+k][p*32+i];
  }
  for(int e=t;e<32*256;e+=256){
    int r=e>>8, c=e&255;
    g.Mm[mat][p*32+r][c]=0.f;
  }
  __syncthreads();
  if(t<32){
    const int j=t;
    float m[32];
    #pragma unroll
    for(int k=0;k<32;k++){
      float s=0.f;
      #pragma unroll
      for(int i=0;i<32;i++) if(i<k) s += Ls[k*33+i]*m[i];
      m[k] = (k<j) ? 0.f : ((k==j) ? 2.f : (-2.f*s));
    }
    #pragma unroll
    for(int k=0;k<32;k++) g.Mm[mat][p*32+k][p*32+j]=m[k];
  }
  __syncthreads();
}

// ---------- merge level S: M21 = -M2 * G21 * M1 (one 32x32 out tile) ----------
template<int S>
__device__ void merge_unit(float* sm, int u){
  constexpr int NT = S/32;
  constexpr int NMG = 128/S;
  constexpr int NTILE = NT*NT;
  constexpr int STR = S/8;
  int mat = u/(NMG*NTILE);
  int rem = u%(NMG*NTILE);
  int mg = rem/NTILE;
  int tile = rem%NTILE;
  int tr = tile/NT, tc = tile%NT;
  const int o = mg*2*S;
  float* M2s = sm;
  float* Ts  = sm + 32*(S+1);
  float* Gc  = sm + 32*(S+1) + 32*(S+4);
  float* Mm = &g.Mm[mat][0][0];
  const float* C2m = &g.C2[mat][0][0];
  const int t=threadIdx.x;
  for(int e=t;e<32*S;e+=256){
    int r=e/S, k=e%S;
    M2s[r*(S+1)+k] = Mm[(o+S+tr*32+r)*HID + o+S+k];
  }
  __syncthreads();
  const int r1=t>>3, jq=t&7;
  float acc[STR];
  #pragma unroll
  for(int z=0;z<STR;z++) acc[z]=0.f;
  for(int kc=0;kc<S;kc+=32){
    for(int e=t;e<32*S;e+=256){
      int kk=e/S, jj=e%S;
      Gc[kk*(S+4)+jj] = C2m[(o+S+kc+kk)*HID + o+jj];
    }
    __syncthreads();
    #pragma unroll
    for(int kk=0;kk<32;kk++){
      float mv = M2s[r1*(S+1)+kc+kk];
      #pragma unroll
      for(int z=0;z<STR;z++) acc[z] += mv * Gc[kk*(S+4)+jq*STR+z];
    }
    __syncthreads();
  }
  #pragma unroll
  for(int z=0;z<STR;z++) Ts[r1*(S+4)+jq*STR+z]=acc[z];
  __syncthreads();
  const int r2=t>>3, cq=t&7;
  float oacc[4]={0.f,0.f,0.f,0.f};
  for(int kc=0;kc<S;kc+=32){
    for(int e=t;e<1024;e+=256){
      int kk=e>>5, c=e&31;
      Gc[kk*36+c] = Mm[(o+kc+kk)*HID + o+tc*32+c];
    }
    __syncthreads();
    #pragma unroll
    for(int kk=0;kk<32;kk++){
      float tv = Ts[r2*(S+4)+kc+kk];
      #pragma unroll
      for(int z=0;z<4;z++) oacc[z] += tv * Gc[kk*36+cq*4+z];
    }
    __syncthreads();
  }
  #pragma unroll
  for(int z=0;z<4;z++)
    Mm[(o+S+tr*32+r2)*HID + o+tc*32+cq*4+z] = -oacc[z];
  __syncthreads();
}

// ---------- R-tree level unit (register-hoisted) ----------
__device__ void rlevel_unit(float* sm, int cP, int cin, int cout, int npair, int local){
  const float* P = sel(cP);
  const float* In = sel(cin);
  float* Out = sel(cout);
  const int t=threadIdx.x;
  const int j=local>>3, mt=local&7;
  if(j>=npair){
    const float* src = In + (size_t)(2*j)*(HID*BATCH) + mt*1024;
    float* dst = Out + (size_t)j*(HID*BATCH) + mt*1024;
    *reinterpret_cast<float4*>(dst + t*4) = *reinterpret_cast<const float4*>(src + t*4);
    return;
  }
  const float* B1 = In + (size_t)(2*j+1)*(HID*BATCH);
  const float* D0 = In + (size_t)(2*j)*(HID*BATCH);
  float* C0 = Out + (size_t)j*(HID*BATCH);
  const int m0 = mt*32;
  const int tx=t&15, ty=t>>4;
  const int kk=t>>4, mm=(t&15)*2;
  float2 pR[16], bR[16];
  #pragma unroll
  for(int c=0;c<16;c++){
    const int k0=c*16;
    pR[c] = *reinterpret_cast<const float2*>(&P[(k0+kk)*HID+m0+mm]);
    bR[c] = *reinterpret_cast<const float2*>(&B1[(k0+kk)*BATCH+mm]);
  }
  float* As=sm; float* Bs=sm+576;
  float a00=0.f,a01=0.f,a10=0.f,a11=0.f;
  #pragma unroll 1
  for(int c=0;c<16;c++){
    As[kk*36+mm]=pR[c].x; As[kk*36+mm+1]=pR[c].y;
    Bs[kk*36+mm]=bR[c].x; Bs[kk*36+mm+1]=bR[c].y;
    __syncthreads();
    #pragma unroll
    for(int k2=0;k2<16;k2++){
      float p0=As[k2*36+ty*2], p1=As[k2*36+ty*2+1];
      float b0=Bs[k2*36+tx*2], b1=Bs[k2*36+tx*2+1];
      a00+=p0*b0; a01+=p0*b1; a10+=p1*b0; a11+=p1*b1;
    }
    __syncthreads();
  }
  const int r=m0+ty*2, c2=tx*2;
  C0[r*BATCH+c2]      =D0[r*BATCH+c2]+a00;
  C0[r*BATCH+c2+1]    =D0[r*BATCH+c2+1]+a01;
  C0[(r+1)*BATCH+c2]  =D0[(r+1)*BATCH+c2]+a10;
  C0[(r+1)*BATCH+c2+1]=D0[(r+1)*BATCH+c2+1]+a11;
}

// ---------- CG solve, one RHS per unit ----------
__device__ void cg_solve_unit(float* sm, int bb){
  float* ps = sm;
  float* red = sm + 260;
  const float* Gf = &g.Gfin[0][0];
  const int i = threadIdx.x;
  auto red256 = [&](float v)->float{
    v+=__shfl_down(v,32);v+=__shfl_down(v,16);v+=__shfl_down(v,8);
    v+=__shfl_down(v,4);v+=__shfl_down(v,2);v+=__shfl_down(v,1);
    if((i&63)==0) red[i>>6]=v;
    __syncthreads();
    float r=red[0]+red[1]+red[2]+red[3];
    __syncthreads();
    return r;
  };
  const float dinv = 1.f/Gf[i*(HID+1)];
  float rcur = g.Rb[1][0][i*BATCH+bb];
  ps[i] = dinv*rcur;
  __syncthreads();
  float rz = red256(dinv*rcur*rcur);
  float s1 = 0.f;
  for(int it=0; it<10; it++){
    float ap0=0.f,ap1=0.f,ap2=0.f,ap3=0.f;
    #pragma unroll 4
    for(int k=0;k<HID;k+=4){
      ap0 = fmaf(Gf[k*HID+i],     ps[k],   ap0);
      ap1 = fmaf(Gf[(k+1)*HID+i], ps[k+1], ap1);
      ap2 = fmaf(Gf[(k+2)*HID+i], ps[k+2], ap2);
      ap3 = fmaf(Gf[(k+3)*HID+i], ps[k+3], ap3);
    }
    float ap = (ap0+ap1)+(ap2+ap3);
    float pap = red256(ps[i]*ap);
    float al = rz/fmaxf(pap,1e-30f);
    rcur -= al*ap;
    float rzn = red256(dinv*rcur*rcur);
    s1 += al*rz;
    float be = rzn/fmaxf(rz,1e-30f);
    rz = rzn;
    __syncthreads();
    ps[i] = dinv*rcur + be*ps[i];
    __syncthreads();
  }
  if(i==0) g.s1b[bb]=s1;
  __syncthreads();
}

// =========================== the mono kernel ===========================
__global__ void __launch_bounds__(NTHR, 1)
k_mono(const float* __restrict__ y, const float* __restrict__ logdet,
       const float* __restrict__ Up, const float* __restrict__ Vp,
       const float* __restrict__ alpha, const float* __restrict__ Cm,
       float* __restrict__ out){
  __shared__ float sm[12800];
  const int b = blockIdx.x;
  const int t = threadIdx.x;

  // ---- P0: y^2 | norm(512) | cgram_part(256) | cty(200) | logdet(1) ----
  {
    const float4* y4 = reinterpret_cast<const float4*>(y);
    float s=0.f;
    for(int i=b*NTHR+t; i<(BATCH*SO)/4; i+=NBLK*NTHR){
      float4 v=y4[i]; s+=v.x*v.x+v.y*v.y+v.z*v.z+v.w*v.w;
    }
    float r=blkred(s,sm);
    if(t==0) g.psum[b]=r;
    __syncthreads();
  }
  for(int u=b; u<969; u+=NBLK){
    if(u<512) norm_unit(sm,u,Up,Vp);
    else if(u<768) cgram_part(sm,u-512,Cm);
    else if(u<968) cty_unit(sm,u-768,y,Cm);
    else {
      float s=0.f;
      for(int i=t;i<BATCH*SEQ;i+=256){float v=logdet[i]; s+=v*v;}
      float r=blkred(s,sm);
      if(t==0) g.psum[NBLK]=r;
      __syncthreads();
    }
  }
  gridbar();
  // ---- P1: C2 = ub ub^T (128; diag tiles also mdiag) | Cg reduce (64) ----
  for(int u=b;u<192;u+=NBLK){
    if(u<128){
      int mat=u>>6, tile=u&63;
      sq_tile(sm,mat,mat,4+mat,0,F_TRANSB,tile,alpha);
      if((tile>>3)==(tile&7)){
        __syncthreads();
        mdiag_unit(sm,(mat<<3)|(tile&7));
      }
    } else cgred_unit(u-128);
  }
  gridbar();
  // ---- P2..P4: merge tree ----
  for(int u=b;u<8;u+=NBLK)  merge_unit<32>(sm,u);
  gridbar();
  for(int u=b;u<16;u+=NBLK) merge_unit<64>(sm,u);
  gridbar();
  for(int u=b;u<32;u+=NBLK) merge_unit<128>(sm,u);
  gridbar();
  // ---- P5: ZT = M ub ----
  for(int u=b;u<128;u+=NBLK){ int mat=u>>6; sq_tile(sm,2+mat,mat,6+mat,0,0,u&63,alpha); }
  gridbar();
  // ---- P6: U,V = I - ZT^T ub ----
  for(int u=b;u<128;u+=NBLK){ int mat=u>>6; sq_tile(sm,6+mat,mat,8+mat,0,F_TRANSA|F_NEGID,u&63,alpha); }
  gridbar();
  // ---- P7: A = (U V^T) * S ----
  for(int u=b;u<64;u+=NBLK) sq_tile(sm,8,9,10,0,F_TRANSB|F_SCALECOL,u,alpha);
  gridbar();
  // ---- P8: A2 ; T = A^T Cg ; Zt reduce ----
  for(int u=b;u<178;u+=NBLK){
    if(u<64)       sq_tile(sm,10,10,11,0,0,u,alpha);
    else if(u<128) sq_tile(sm,10,16,19,0,F_TRANSA,u-64,alpha);
    else           ztred_unit(u-128);
  }
  gridbar();
  // ---- P9: G2 = Cg + T A ; A4 ; R1 (P=A, Zt->Rb0, 25 pairs) ----
  for(int u=b;u<328;u+=NBLK){
    if(u<64)       sq_tile(sm,19,10,17,16,F_ACC,u,alpha);
    else if(u<128) sq_tile(sm,11,11,12,0,0,u-64,alpha);
    else           rlevel_unit(sm,10,24,25,25,u-128);
  }
  gridbar();
  // ---- P10: T = A2^T G2 ; A8 ; R2 (P=A2, Rb0->Rb1, 12 pairs of 25) ----
  for(int u=b;u<232;u+=NBLK){
    if(u<64)       sq_tile(sm,11,17,19,0,F_TRANSA,u,alpha);
    else if(u<128) sq_tile(sm,12,12,13,0,0,u-64,alpha);
    else           rlevel_unit(sm,11,25,26,12,u-128);
  }
  gridbar();
  // ---- P11: G4 = G2 + T A2 ; A16 ; R3 (P=A4, Rb1->Rb0, 6 pairs of 13) ----
  for(int u=b;u<184;u+=NBLK){
    if(u<64)       sq_tile(sm,19,11,18,17,F_ACC,u,alpha);
    else if(u<128) sq_tile(sm,13,13,14,0,0,u-64,alpha);
    else           rlevel_unit(sm,12,26,25,6,u-128);
  }
  gridbar();
  // ---- P12: T = A4^T G4 ; A32 ; R4 (P=A8, Rb0->Rb1, 3 pairs of 7) ----
  for(int u=b;u<160;u+=NBLK){
    if(u<64)       sq_tile(sm,12,18,19,0,F_TRANSA,u,alpha);
    else if(u<128) sq_tile(sm,14,14,15,0,0,u-64,alpha);
    else           rlevel_unit(sm,13,25,26,3,u-128);
  }
  gridbar();
  // ---- P13: G8 = G4 + T A4 ; R5 (P=A16, Rb1->Rb0, 2 pairs of 4) ----
  for(int u=b;u<80;u+=NBLK){
    if(u<64) sq_tile(sm,19,12,18,18,F_ACC,u,alpha);
    else     rlevel_unit(sm,14,26,25,2,u-64);
  }
  gridbar();
  // ---- P14: T = A8^T G8 ; R6 (P=A32, Rb0->Rb1, 1 pair of 2) ----
  for(int u=b;u<72;u+=NBLK){
    if(u<64) sq_tile(sm,13,18,19,0,F_TRANSA,u,alpha);
    else     rlevel_unit(sm,15,25,26,1,u-64);
  }
  gridbar();
  // ---- P15: G16 = G8 + T A8 ----
  for(int u=b;u<64;u+=NBLK) sq_tile(sm,19,13,18,18,F_ACC,u,alpha);
  gridbar();
  // ---- P16: T = A16^T G16 ; T2 = A16^T G2 ----
  for(int u=b;u<128;u+=NBLK){
    if(u<64) sq_tile(sm,14,18,19,0,F_TRANSA,u,alpha);
    else     sq_tile(sm,14,17,20,0,F_TRANSA,u-64,alpha);
  }
  gridbar();
  // ---- P17: G32 = G16 + T A16 ; G18 = G16 + T2 A16 ----
  for(int u=b;u<128;u+=NBLK){
    if(u<64) sq_tile(sm,19,14,22,18,F_ACC,u,alpha);
    else     sq_tile(sm,20,14,21,18,F_ACC,u-64,alpha);
  }
  gridbar();
  // ---- P18: T = A32^T G18 ----
  for(int u=b;u<64;u+=NBLK) sq_tile(sm,15,21,19,0,F_TRANSA,u,alpha);
  gridbar();
  // ---- P19: Gfin = G32 + T A32 ----
  for(int u=b;u<64;u+=NBLK) sq_tile(sm,19,15,23,22,F_ACC,u,alpha);
  gridbar();
  // ---- P20: CG (32 independent RHS) ----
  for(int u=b;u<BATCH;u+=NBLK) cg_solve_unit(sm,u);
  gridbar();
  // ---- P21: final loss ----
  if(b==0){
    float r = blkred(g.psum[t], sm);
    if(t==0){
      float t1=0.f;
      for(int q=0;q<BATCH;q++) t1+=g.s1b[q];
      float sld = g.psum[NBLK];
      float mw = (r - t1)/(float)(SO*BATCH);
      out[0] = 0.5f*mw + sld/((float)(BATCH*SEQ)*(float)OBS*(float)OBS);
    }
  }
}

extern "C" void kernel_launch(void* const* d_in, const int* in_sizes, int n_in,
                              void* d_out, int out_size, void* d_ws, size_t ws_size,
                              hipStream_t stream){
  const float* y      = (const float*)d_in[0];
  const float* logdet = (const float*)d_in[1];
  const float* Up     = (const float*)d_in[2];
  const float* Vp     = (const float*)d_in[3];
  const float* alpha  = (const float*)d_in[4];
  const float* Cm     = (const float*)d_in[5];
  float* outp = (float*)d_out;

  k_mono<<<dim3(NBLK), dim3(NTHR), 0, stream>>>(y, logdet, Up, Vp, alpha, Cm, outp);
}

// Round 11
// 830.331 us; speedup vs baseline: 1.5482x; 1.5482x over previous
//
#include <hip/hip_runtime.h>

#define HID 256
#define OBS 1024
#define SEQ 50
#define BATCH 32
#define SO (SEQ*OBS)   // 51200

#define F_TRANSA   1
#define F_NEGID    2
#define F_ACC      4
#define F_TRANSB   8
#define F_SCALECOL 16
#define F_RLEVEL   32

struct DevWS {
  float ub[2][HID][HID];     // 0,1  normalized reflectors (bitrev order)
  float Mm[2][HID][HID];     // 2,3  M = 2(I+2L)^-1, lower triangular
  float C2[2][HID][HID];     // 4,5  reflector Gram
  float ZT[2][HID][HID];     // 6,7  ZT = M @ ub
  float U[HID][HID];         // 8
  float V[HID][HID];         // 9
  float A[HID][HID];         // 10
  float A2[HID][HID];        // 11
  float A4[HID][HID];        // 12
  float A8[HID][HID];        // 13
  float A16[HID][HID];       // 14
  float A32[HID][HID];       // 15
  float Cg[HID][HID];        // 16  C^T C
  float G2[HID][HID];        // 17
  float Grun[HID][HID];      // 18
  float T[HID][HID];         // 19
  float T2[HID][HID];        // 20
  float G18[HID][HID];       // 21
  float G32b[HID][HID];      // 22
  float Gfin[HID][HID];      // 23
  float Zt4[SEQ][4][HID*BATCH];   // partial C^T Y_t per obs-quarter
  float Zt[SEQ][HID*BATCH];       // 24 reduced
  float Rb[2][25][HID*BATCH];     // 25,26 R-tree ping-pong
  float psum[513];                // y^2 partials [0..512), logdet^2 [512]
  float s1b[BATCH];               // per-rhs sum alpha_j*rz_j
};
__device__ DevWS g;

__device__ __forceinline__ float* sel(int c){
  switch(c){
    case 0:  return &g.ub[0][0][0];
    case 1:  return &g.ub[1][0][0];
    case 2:  return &g.Mm[0][0][0];
    case 3:  return &g.Mm[1][0][0];
    case 4:  return &g.C2[0][0][0];
    case 5:  return &g.C2[1][0][0];
    case 6:  return &g.ZT[0][0][0];
    case 7:  return &g.ZT[1][0][0];
    case 8:  return &g.U[0][0];
    case 9:  return &g.V[0][0];
    case 10: return &g.A[0][0];
    case 11: return &g.A2[0][0];
    case 12: return &g.A4[0][0];
    case 13: return &g.A8[0][0];
    case 14: return &g.A16[0][0];
    case 15: return &g.A32[0][0];
    case 16: return &g.Cg[0][0];
    case 17: return &g.G2[0][0];
    case 18: return &g.Grun[0][0];
    case 19: return &g.T[0][0];
    case 20: return &g.T2[0][0];
    case 21: return &g.G18[0][0];
    case 22: return &g.G32b[0][0];
    case 23: return &g.Gfin[0][0];
    case 24: return &g.Zt[0][0];
    case 25: return &g.Rb[0][0][0];
    default: return &g.Rb[1][0][0];
  }
}

__device__ __forceinline__ int bitrev8(int x){
  x = ((x & 0x55) << 1) | ((x >> 1) & 0x55);
  x = ((x & 0x33) << 2) | ((x >> 2) & 0x33);
  x = ((x & 0x0F) << 4) | ((x >> 4) & 0x0F);
  return x;
}

__device__ __forceinline__ float blkred(float v, float* sm){
  v += __shfl_down(v,32); v += __shfl_down(v,16); v += __shfl_down(v,8);
  v += __shfl_down(v,4);  v += __shfl_down(v,2);  v += __shfl_down(v,1);
  const int t = threadIdx.x;
  if((t&63)==0) sm[t>>6] = v;
  __syncthreads();
  float r = sm[0]+sm[1]+sm[2]+sm[3];
  __syncthreads();
  return r;
}

// ---------- 32x32-tile GEMM unit, register-hoisted loads (R10-proven) ----------
__device__ void sq_tile(float* sm, int cA,int cB,int cC,int cD,int flags,int local,
                        const float* __restrict__ alpha){
  const float* A = sel(cA);
  const float* B = sel(cB);
  float* Cp = sel(cC);
  const float* Dp = sel(cD);
  float* As = sm; float* Bs = sm + 576;
  const int t = threadIdx.x, tx = t&15, ty = t>>4;
  const int m0 = (local>>3)*32, n0 = (local&7)*32;

  float2 aR[16], bR[16];
  #pragma unroll
  for(int c=0;c<16;c++){
    const int k0 = c*16;
    if(flags & F_TRANSA){
      int kk=t>>4, mm=(t&15)*2;
      aR[c] = *reinterpret_cast<const float2*>(&A[(k0+kk)*HID+m0+mm]);
    } else {
      int r=t>>3, cc=(t&7)*2;
      aR[c] = *reinterpret_cast<const float2*>(&A[(m0+r)*HID+k0+cc]);
    }
    if(flags & F_TRANSB){
      int cb=t>>3, rb=(t&7)*2;
      bR[c] = *reinterpret_cast<const float2*>(&B[(n0+cb)*HID+k0+rb]);
    } else {
      int rb=t>>4, cb=(t&15)*2;
      bR[c] = *reinterpret_cast<const float2*>(&B[(k0+rb)*HID+n0+cb]);
    }
  }
  float a00=0.f,a01=0.f,a10=0.f,a11=0.f;
  #pragma unroll 1
  for(int c=0;c<16;c++){
    if(flags & F_TRANSA){
      int kk=t>>4, mm=(t&15)*2;
      As[kk*36+mm]=aR[c].x; As[kk*36+mm+1]=aR[c].y;
    } else {
      int r=t>>3, cc=(t&7)*2;
      As[cc*36+r]=aR[c].x; As[(cc+1)*36+r]=aR[c].y;
    }
    if(flags & F_TRANSB){
      int cb=t>>3, rb=(t&7)*2;
      Bs[rb*36+cb]=bR[c].x; Bs[(rb+1)*36+cb]=bR[c].y;
    } else {
      int rb=t>>4, cb=(t&15)*2;
      Bs[rb*36+cb]=bR[c].x; Bs[rb*36+cb+1]=bR[c].y;
    }
    __syncthreads();
    #pragma unroll
    for(int kk=0;kk<16;kk++){
      float x0=As[kk*36+ty*2], x1=As[kk*36+ty*2+1];
      float y0=Bs[kk*36+tx*2], y1=Bs[kk*36+tx*2+1];
      a00+=x0*y0; a01+=x0*y1; a10+=x1*y0; a11+=x1*y1;
    }
    __syncthreads();
  }
  const int r=m0+ty*2, c=n0+tx*2;
  float v00=a00,v01=a01,v10=a10,v11=a11;
  if(flags & F_ACC){
    v00+=Dp[r*HID+c]; v01+=Dp[r*HID+c+1];
    v10+=Dp[(r+1)*HID+c]; v11+=Dp[(r+1)*HID+c+1];
  }
  if(flags & F_SCALECOL){
    float s0=1.f-fminf(fabsf(alpha[c]),1.f);
    float s1=1.f-fminf(fabsf(alpha[c+1]),1.f);
    v00*=s0; v01*=s1; v10*=s0; v11*=s1;
  }
  if(flags & F_NEGID){
    v00=((r==c)?1.f:0.f)-v00;   v01=((r==c+1)?1.f:0.f)-v01;
    v10=((r+1==c)?1.f:0.f)-v10; v11=((r+1==c+1)?1.f:0.f)-v11;
  }
  Cp[r*HID+c]=v00; Cp[r*HID+c+1]=v01;
  Cp[(r+1)*HID+c]=v10; Cp[(r+1)*HID+c+1]=v11;
}

// ---------- Cg = C^T C tile (K=1024, R3-proven) ----------
__device__ void cgram_tile(float* sm, int tile, const float* __restrict__ Cm){
  float* As = sm; float* Bs = sm + 576;
  const int t = threadIdx.x, tx = t&15, ty = t>>4;
  const int m0=(tile>>3)*32, n0=(tile&7)*32;
  float a00=0.f,a01=0.f,a10=0.f,a11=0.f;
  for(int o0=0;o0<OBS;o0+=16){
    int r=t>>4, cp=(t&15)*2;
    float2 a=*reinterpret_cast<const float2*>(&Cm[(o0+r)*HID+m0+cp]);
    As[r*36+cp]=a.x; As[r*36+cp+1]=a.y;
    float2 b2=*reinterpret_cast<const float2*>(&Cm[(o0+r)*HID+n0+cp]);
    Bs[r*36+cp]=b2.x; Bs[r*36+cp+1]=b2.y;
    __syncthreads();
    #pragma unroll
    for(int kk=0;kk<16;kk++){
      float x0=As[kk*36+ty*2], x1=As[kk*36+ty*2+1];
      float y0=Bs[kk*36+tx*2], y1=Bs[kk*36+tx*2+1];
      a00+=x0*y0; a01+=x0*y1; a10+=x1*y0; a11+=x1*y1;
    }
    __syncthreads();
  }
  g.Cg[m0+ty*2][n0+tx*2]=a00;   g.Cg[m0+ty*2][n0+tx*2+1]=a01;
  g.Cg[m0+ty*2+1][n0+tx*2]=a10; g.Cg[m0+ty*2+1][n0+tx*2+1]=a11;
}

// ---------- normalize one reflector row ----------
__device__ void norm_unit(float* sm, int u, const float* __restrict__ Up,
                          const float* __restrict__ Vp){
  int mat=u>>8, j=u&255, src=bitrev8(j);
  const float* P = mat ? Vp : Up;
  int t=threadIdx.x;
  float x = P[src*HID + t];
  float ss = blkred(x*x, sm);
  g.ub[mat][j][t] = x * rsqrtf(ss);
}

// ---------- CtY quarter (R7-proven, 256 threads) ----------
__device__ void cty_unit(float* sm, int u, const float* __restrict__ y,
                         const float* __restrict__ Cm){
  int tt=u>>2, ot=u&3;
  float* ys = sm;   // [256][36]
  const int t=threadIdx.x;
  for(int e=t;e<8192;e+=256){
    int b=e>>8, o=e&255;
    ys[o*36+b] = y[b*SO + tt*OBS + ot*256 + o];
  }
  __syncthreads();
  const int h=t;
  float acc[32];
  #pragma unroll
  for(int z=0;z<32;z++) acc[z]=0.f;
  for(int o=0;o<256;o++){
    float cv = Cm[(ot*256+o)*HID + h];
    #pragma unroll
    for(int bb=0;bb<32;bb+=4){
      float4 v=*reinterpret_cast<const float4*>(&ys[o*36+bb]);
      acc[bb]+=cv*v.x; acc[bb+1]+=cv*v.y; acc[bb+2]+=cv*v.z; acc[bb+3]+=cv*v.w;
    }
  }
  float* outp = &g.Zt4[tt][ot][h*BATCH];
  #pragma unroll
  for(int bb=0;bb<32;bb+=4){
    float4 w={acc[bb],acc[bb+1],acc[bb+2],acc[bb+3]};
    *reinterpret_cast<float4*>(&outp[bb])=w;
  }
  __syncthreads();
}

// ---------- Zt[tt] = sum of 4 obs-quarter partials (R9-proven) ----------
__device__ void ztred_unit(int u){
  const int t=threadIdx.x;
  const float* z=&g.Zt4[u][0][0];
  float* o=&g.Zt[u][0];
  for(int e=t*4; e<HID*BATCH; e+=256*4){
    float4 a=*reinterpret_cast<const float4*>(&z[e]);
    float4 b=*reinterpret_cast<const float4*>(&z[HID*BATCH+e]);
    float4 c=*reinterpret_cast<const float4*>(&z[2*HID*BATCH+e]);
    float4 d=*reinterpret_cast<const float4*>(&z[3*HID*BATCH+e]);
    float4 r; r.x=(a.x+b.x)+(c.x+d.x); r.y=(a.y+b.y)+(c.y+d.y);
    r.z=(a.z+b.z)+(c.z+d.z); r.w=(a.w+b.w)+(c.w+d.w);
    *reinterpret_cast<float4*>(&o[e])=r;
  }
}

// ---------- M diag: 32x32 forward substitution (R7/R9/R10-proven) ----------
__device__ void mdiag_unit(float* sm, int u){
  int mat=u>>3, p=u&7;
  float* Ls = sm; // [32][33]
  const int t=threadIdx.x;
  for(int e=t;e<1024;e+=256){
    int k=e>>5, i=e&31;
    Ls[k*33+i] = g.C2[mat][p*32+k][p*32+i];
  }
  for(int e=t;e<32*256;e+=256){
    int r=e>>8, c=e&255;
    g.Mm[mat][p*32+r][c]=0.f;
  }
  __syncthreads();
  if(t<32){
    const int j=t;
    float m[32];
    #pragma unroll
    for(int k=0;k<32;k++){
      float s=0.f;
      #pragma unroll
      for(int i=0;i<32;i++) if(i<k) s += Ls[k*33+i]*m[i];
      m[k] = (k<j) ? 0.f : ((k==j) ? 2.f : (-2.f*s));
    }
    #pragma unroll
    for(int k=0;k<32;k++) g.Mm[mat][p*32+k][p*32+j]=m[k];
  }
  __syncthreads();
}

// ---------- merge level S: M21 = -M2 * C2_21 * M1 (R7/R9/R10-proven) ----------
template<int S>
__device__ void merge_unit(float* sm, int u){
  constexpr int NT = S/32;
  constexpr int NMG = 128/S;
  constexpr int NTILE = NT*NT;
  constexpr int STR = S/8;
  int mat = u/(NMG*NTILE);
  int rem = u%(NMG*NTILE);
  int mg = rem/NTILE;
  int tile = rem%NTILE;
  int tr = tile/NT, tc = tile%NT;
  const int o = mg*2*S;
  float* M2s = sm;
  float* Ts  = sm + 32*(S+1);
  float* Gc  = sm + 32*(S+1) + 32*(S+4);
  float* Mm = &g.Mm[mat][0][0];
  const float* C2m = &g.C2[mat][0][0];
  const int t=threadIdx.x;
  for(int e=t;e<32*S;e+=256){
    int r=e/S, k=e%S;
    M2s[r*(S+1)+k] = Mm[(o+S+tr*32+r)*HID + o+S+k];
  }
  __syncthreads();
  const int r1=t>>3, jq=t&7;
  float acc[STR];
  #pragma unroll
  for(int z=0;z<STR;z++) acc[z]=0.f;
  for(int kc=0;kc<S;kc+=32){
    for(int e=t;e<32*S;e+=256){
      int kk=e/S, jj=e%S;
      Gc[kk*(S+4)+jj] = C2m[(o+S+kc+kk)*HID + o+jj];
    }
    __syncthreads();
    #pragma unroll
    for(int kk=0;kk<32;kk++){
      float mv = M2s[r1*(S+1)+kc+kk];
      #pragma unroll
      for(int z=0;z<STR;z++) acc[z] += mv * Gc[kk*(S+4)+jq*STR+z];
    }
    __syncthreads();
  }
  #pragma unroll
  for(int z=0;z<STR;z++) Ts[r1*(S+4)+jq*STR+z]=acc[z];
  __syncthreads();
  const int r2=t>>3, cq=t&7;
  float oacc[4]={0.f,0.f,0.f,0.f};
  for(int kc=0;kc<S;kc+=32){
    for(int e=t;e<1024;e+=256){
      int kk=e>>5, c=e&31;
      Gc[kk*36+c] = Mm[(o+kc+kk)*HID + o+tc*32+c];
    }
    __syncthreads();
    #pragma unroll
    for(int kk=0;kk<32;kk++){
      float tv = Ts[r2*(S+4)+kc+kk];
      #pragma unroll
      for(int z=0;z<4;z++) oacc[z] += tv * Gc[kk*36+cq*4+z];
    }
    __syncthreads();
  }
  #pragma unroll
  for(int z=0;z<4;z++)
    Mm[(o+S+tr*32+r2)*HID + o+tc*32+cq*4+z] = -oacc[z];
  __syncthreads();
}

// ---------- R-tree level unit (R10-proven, register-hoisted) ----------
__device__ void rlevel_unit(float* sm, int cP, int cin, int cout, int npair, int local){
  const float* P = sel(cP);
  const float* In = sel(cin);
  float* Out = sel(cout);
  const int t=threadIdx.x;
  const int j=local>>3, mt=local&7;
  if(j>=npair){
    const float* src = In + (size_t)(2*j)*(HID*BATCH) + mt*1024;
    float* dst = Out + (size_t)j*(HID*BATCH) + mt*1024;
    *reinterpret_cast<float4*>(dst + t*4) = *reinterpret_cast<const float4*>(src + t*4);
    return;
  }
  const float* B1 = In + (size_t)(2*j+1)*(HID*BATCH);
  const float* D0 = In + (size_t)(2*j)*(HID*BATCH);
  float* C0 = Out + (size_t)j*(HID*BATCH);
  const int m0 = mt*32;
  const int tx=t&15, ty=t>>4;
  const int kk=t>>4, mm=(t&15)*2;
  float2 pR[16], bR[16];
  #pragma unroll
  for(int c=0;c<16;c++){
    const int k0=c*16;
    pR[c] = *reinterpret_cast<const float2*>(&P[(k0+kk)*HID+m0+mm]);
    bR[c] = *reinterpret_cast<const float2*>(&B1[(k0+kk)*BATCH+mm]);
  }
  float* As=sm; float* Bs=sm+576;
  float a00=0.f,a01=0.f,a10=0.f,a11=0.f;
  #pragma unroll 1
  for(int c=0;c<16;c++){
    As[kk*36+mm]=pR[c].x; As[kk*36+mm+1]=pR[c].y;
    Bs[kk*36+mm]=bR[c].x; Bs[kk*36+mm+1]=bR[c].y;
    __syncthreads();
    #pragma unroll
    for(int k2=0;k2<16;k2++){
      float p0=As[k2*36+ty*2], p1=As[k2*36+ty*2+1];
      float b0=Bs[k2*36+tx*2], b1=Bs[k2*36+tx*2+1];
      a00+=p0*b0; a01+=p0*b1; a10+=p1*b0; a11+=p1*b1;
    }
    __syncthreads();
  }
  const int r=m0+ty*2, c2=tx*2;
  C0[r*BATCH+c2]      =D0[r*BATCH+c2]+a00;
  C0[r*BATCH+c2+1]    =D0[r*BATCH+c2+1]+a01;
  C0[(r+1)*BATCH+c2]  =D0[(r+1)*BATCH+c2]+a10;
  C0[(r+1)*BATCH+c2+1]=D0[(r+1)*BATCH+c2+1]+a11;
}

// ================= kernels =================
struct GD { int cA, cB, cC, cD, flags, npair; };
struct GArgs { GD d[4]; int pre[4]; int nd; };

__global__ __launch_bounds__(256) void k_gemmN(GArgs ga, const float* __restrict__ alpha){
  __shared__ float sm[1152];
  int blk = blockIdx.x;
  int di = 0;
  #pragma unroll
  for(int s=1;s<4;s++) if(ga.nd > s && blk >= ga.pre[s]) di = s;
  const GD d = ga.d[di];
  const int local = blk - ga.pre[di];
  if(d.flags & F_RLEVEL){ rlevel_unit(sm, d.cA, d.cB, d.cC, d.npair, local); return; }
  sq_tile(sm, d.cA, d.cB, d.cC, d.cD, d.flags, local, alpha);
}

__global__ __launch_bounds__(256) void k_prep(const float* __restrict__ y,
                                              const float* __restrict__ logdet,
                                              const float* __restrict__ Up,
                                              const float* __restrict__ Vp,
                                              const float* __restrict__ Cm){
  __shared__ float sm[9216];
  const int bx = blockIdx.x;
  const int t = threadIdx.x;
  if(bx < 512){ norm_unit(sm, bx, Up, Vp); return; }
  if(bx < 1024){
    int bi = bx - 512;
    const float4* y4 = reinterpret_cast<const float4*>(y);
    const int n4 = (BATCH*SO)/4;
    float s = 0.f;
    for(int i = bi*256 + t; i < n4; i += 512*256){
      float4 v = y4[i];
      s += v.x*v.x + v.y*v.y + v.z*v.z + v.w*v.w;
    }
    float r = blkred(s, sm);
    if(t==0) g.psum[bi] = r;
    return;
  }
  if(bx == 1024){
    float s = 0.f;
    for(int i = t; i < BATCH*SEQ; i += 256){ float v = logdet[i]; s += v*v; }
    float r = blkred(s, sm);
    if(t==0) g.psum[512] = r;
    return;
  }
  if(bx < 1089){ cgram_tile(sm, bx-1025, Cm); return; }
  cty_unit(sm, bx-1089, y, Cm);
}

__global__ __launch_bounds__(256) void k_front2(const float* __restrict__ alpha){
  __shared__ float sm[1152];
  const int u = blockIdx.x;
  if(u < 128){
    int mat = u>>6, tile = u&63;
    sq_tile(sm, mat, mat, 4+mat, 4+mat, F_TRANSB, tile, alpha);   // C2 = ub ub^T
    if((tile>>3) == (tile&7)){
      __syncthreads();
      mdiag_unit(sm, (mat<<3)|(tile&7));
    }
    return;
  }
  ztred_unit(u-128);
}

__global__ __launch_bounds__(256) void k_mtree(){
  __shared__ float sm[12800];
  const int mat = blockIdx.x;
  for(int mg=0; mg<4; mg++)  merge_unit<32>(sm, mat*4 + mg);
  for(int u2=0; u2<8; u2++)  merge_unit<64>(sm, mat*8 + u2);
  for(int u2=0; u2<16; u2++) merge_unit<128>(sm, mat*16 + u2);
}

__global__ __launch_bounds__(256) void k_cg(){
  __shared__ float sm[264];
  float* ps = sm;
  float* red = sm + 260;
  const float* Gf = &g.Gfin[0][0];
  const int i = threadIdx.x;
  const int bb = blockIdx.x;
  auto red256 = [&](float v)->float{
    v+=__shfl_down(v,32);v+=__shfl_down(v,16);v+=__shfl_down(v,8);
    v+=__shfl_down(v,4);v+=__shfl_down(v,2);v+=__shfl_down(v,1);
    if((i&63)==0) red[i>>6]=v;
    __syncthreads();
    float r=red[0]+red[1]+red[2]+red[3];
    __syncthreads();
    return r;
  };
  const float dinv = 1.f/Gf[i*(HID+1)];
  float rcur = g.Rb[1][0][i*BATCH+bb];
  ps[i] = dinv*rcur;
  __syncthreads();
  float rz = red256(dinv*rcur*rcur);
  float s1 = 0.f;
  for(int it=0; it<10; it++){
    float ap0=0.f,ap1=0.f,ap2=0.f,ap3=0.f;
    #pragma unroll 4
    for(int k=0;k<HID;k+=4){
      ap0 = fmaf(Gf[k*HID+i],     ps[k],   ap0);
      ap1 = fmaf(Gf[(k+1)*HID+i], ps[k+1], ap1);
      ap2 = fmaf(Gf[(k+2)*HID+i], ps[k+2], ap2);
      ap3 = fmaf(Gf[(k+3)*HID+i], ps[k+3], ap3);
    }
    float ap = (ap0+ap1)+(ap2+ap3);
    float pap = red256(ps[i]*ap);
    float al = rz/fmaxf(pap,1e-30f);
    rcur -= al*ap;
    float rzn = red256(dinv*rcur*rcur);
    s1 += al*rz;
    float be = rzn/fmaxf(rz,1e-30f);
    rz = rzn;
    __syncthreads();
    ps[i] = dinv*rcur + be*ps[i];
    __syncthreads();
  }
  if(i==0) g.s1b[bb]=s1;
}

__global__ __launch_bounds__(256) void k_fin(float* __restrict__ out){
  __shared__ float sm[4];
  const int t = threadIdx.x;
  float s = g.psum[t] + g.psum[t+256];
  float r = blkred(s, sm);
  if(t==0){
    float t1=0.f;
    for(int q=0;q<BATCH;q++) t1+=g.s1b[q];
    float sld = g.psum[512];
    float mw = (r - t1)/(float)(SO*BATCH);
    out[0] = 0.5f*mw + sld/((float)(BATCH*SEQ)*(float)OBS*(float)OBS);
  }
}

// ================= host side =================
struct LB { GArgs ga; int total; };
static inline GD sq(int cA,int cB,int cC,int cD,int flags){ GD d; d.cA=cA;d.cB=cB;d.cC=cC;d.cD=cD;d.flags=flags;d.npair=0; return d; }
static inline GD rl(int cP,int cin,int cout,int npair){ GD d; d.cA=cP;d.cB=cin;d.cC=cout;d.cD=0;d.flags=F_RLEVEL;d.npair=npair; return d; }
static inline LB mkN(const GD* ds, const int* bs, int n){
  LB l; int acc=0;
  for(int i=0;i<4;i++){ l.ga.pre[i]=0; }
  for(int i=0;i<n;i++){ l.ga.d[i]=ds[i]; l.ga.pre[i]=acc; acc+=bs[i]; }
  l.ga.nd=n; l.total=acc; return l;
}

extern "C" void kernel_launch(void* const* d_in, const int* in_sizes, int n_in,
                              void* d_out, int out_size, void* d_ws, size_t ws_size,
                              hipStream_t stream){
  const float* y      = (const float*)d_in[0];
  const float* logdet = (const float*)d_in[1];
  const float* Up     = (const float*)d_in[2];
  const float* Vp     = (const float*)d_in[3];
  const float* alpha  = (const float*)d_in[4];
  const float* Cm     = (const float*)d_in[5];
  float* outp = (float*)d_out;

  // L1: norm + y^2 + logdet + Cg + CtY quarters
  k_prep<<<dim3(1289), dim3(256), 0, stream>>>(y, logdet, Up, Vp, Cm);
  // L2: C2 (diag tiles also mdiag) + Zt reduce
  k_front2<<<dim3(178), dim3(256), 0, stream>>>(alpha);
  // L3: full merge tree (one block per matrix)
  k_mtree<<<dim3(2), dim3(256), 0, stream>>>();
  // L4: ZT = M @ ub (x2)
  { GD ds[2]={sq(2,0,6,6,0), sq(3,1,7,7,0)}; int bs[2]={64,64};
    LB l=mkN(ds,bs,2); k_gemmN<<<l.total,256,0,stream>>>(l.ga, alpha); }
  // L5: U,V = I - ZT^T ub
  { GD ds[2]={sq(6,0,8,8,F_TRANSA|F_NEGID), sq(7,1,9,9,F_TRANSA|F_NEGID)}; int bs[2]={64,64};
    LB l=mkN(ds,bs,2); k_gemmN<<<l.total,256,0,stream>>>(l.ga, alpha); }
  // L6: A = (U V^T) * S
  { GD ds[1]={sq(8,9,10,10,F_TRANSB|F_SCALECOL)}; int bs[1]={64};
    LB l=mkN(ds,bs,1); k_gemmN<<<l.total,256,0,stream>>>(l.ga, alpha); }
  // L7: A2 ; T = A^T Cg
  { GD ds[2]={sq(10,10,11,11,0), sq(10,16,19,19,F_TRANSA)}; int bs[2]={64,64};
    LB l=mkN(ds,bs,2); k_gemmN<<<l.total,256,0,stream>>>(l.ga, alpha); }
  // L8: G2 = Cg + T A ; A4 ; R1 (P=A, Zt->Rb0, 25 pairs)
  { GD ds[3]={sq(19,10,17,16,F_ACC), sq(11,11,12,12,0), rl(10,24,25,25)}; int bs[3]={64,64,200};
    LB l=mkN(ds,bs,3); k_gemmN<<<l.total,256,0,stream>>>(l.ga, alpha); }
  // L9: T = A2^T G2 ; A8 ; R2 (P=A2, Rb0->Rb1, 12 pairs of 25)
  { GD ds[3]={sq(11,17,19,19,F_TRANSA), sq(12,12,13,13,0), rl(11,25,26,12)}; int bs[3]={64,64,104};
    LB l=mkN(ds,bs,3); k_gemmN<<<l.total,256,0,stream>>>(l.ga, alpha); }
  // L10: G4 = G2 + T A2 ; A16 ; R3 (P=A4, Rb1->Rb0, 6 pairs of 13)
  { GD ds[3]={sq(19,11,18,17,F_ACC), sq(13,13,14,14,0), rl(12,26,25,6)}; int bs[3]={64,64,56};
    LB l=mkN(ds,bs,3); k_gemmN<<<l.total,256,0,stream>>>(l.ga, alpha); }
  // L11: T = A4^T G4 ; A32 ; R4 (P=A8, Rb0->Rb1, 3 pairs of 7)
  { GD ds[3]={sq(12,18,19,19,F_TRANSA), sq(14,14,15,15,0), rl(13,25,26,3)}; int bs[3]={64,64,32};
    LB l=mkN(ds,bs,3); k_gemmN<<<l.total,256,0,stream>>>(l.ga, alpha); }
  // L12: G8 = G4 + T A4 ; R5 (P=A16, Rb1->Rb0, 2 pairs of 4)
  { GD ds[2]={sq(19,12,18,18,F_ACC), rl(14,26,25,2)}; int bs[2]={64,16};
    LB l=mkN(ds,bs,2); k_gemmN<<<l.total,256,0,stream>>>(l.ga, alpha); }
  // L13: T = A8^T G8 ; R6 (P=A32, Rb0->Rb1, 1 pair of 2)
  { GD ds[2]={sq(13,18,19,19,F_TRANSA), rl(15,25,26,1)}; int bs[2]={64,8};
    LB l=mkN(ds,bs,2); k_gemmN<<<l.total,256,0,stream>>>(l.ga, alpha); }
  // L14: G16 = G8 + T A8
  { GD ds[1]={sq(19,13,18,18,F_ACC)}; int bs[1]={64};
    LB l=mkN(ds,bs,1); k_gemmN<<<l.total,256,0,stream>>>(l.ga, alpha); }
  // L15: T = A16^T G16 ; T2 = A16^T G2
  { GD ds[2]={sq(14,18,19,19,F_TRANSA), sq(14,17,20,20,F_TRANSA)}; int bs[2]={64,64};
    LB l=mkN(ds,bs,2); k_gemmN<<<l.total,256,0,stream>>>(l.ga, alpha); }
  // L16: G32 = G16 + T A16 ; G18 = G16 + T2 A16
  { GD ds[2]={sq(19,14,22,18,F_ACC), sq(20,14,21,18,F_ACC)}; int bs[2]={64,64};
    LB l=mkN(ds,bs,2); k_gemmN<<<l.total,256,0,stream>>>(l.ga, alpha); }
  // L17: T = A32^T G18
  { GD ds[1]={sq(15,21,19,19,F_TRANSA)}; int bs[1]={64};
    LB l=mkN(ds,bs,1); k_gemmN<<<l.total,256,0,stream>>>(l.ga, alpha); }
  // L18: Gfin = G32 + T A32
  { GD ds[1]={sq(19,15,23,22,F_ACC)}; int bs[1]={64};
    LB l=mkN(ds,bs,1); k_gemmN<<<l.total,256,0,stream>>>(l.ga, alpha); }
  // L19: CG (32 independent RHS)
  k_cg<<<dim3(32), dim3(256), 0, stream>>>();
  // L20: final loss
  k_fin<<<dim3(1), dim3(256), 0, stream>>>(outp);
}